// Round 5
// baseline (49.022 us; speedup 1.0000x reference)
//
#include <hip/hip_runtime.h>

#define B_ 2048
#define V_ 2048
#define C_ 512
#define M_ 8
#define H_ 16
#define NB 2            // rows per compute block
#define CHUNK 256       // columns per compute block == blockDim.x
#define NCOMPUTE ((C_ / CHUNK) * (B_ / NB))   // 2048 compute blocks
#define NCOPY (B_ / 2)                        // 1024 copy blocks, 2 rows each

typedef float f32x2 __attribute__((ext_vector_type(2)));

__device__ __forceinline__ float fast_exp2(float x) { return __builtin_amdgcn_exp2f(x); }
__device__ __forceinline__ float fast_rcp(float x)  { return __builtin_amdgcn_rcpf(x); }

#define LOG2E 1.4426950408889634f

// Guaranteed VOP3P packed fp32 (compiler refuses to auto-emit these).
__device__ __forceinline__ f32x2 pk_fma(f32x2 a, f32x2 b, f32x2 c) {
    f32x2 d; asm("v_pk_fma_f32 %0, %1, %2, %3" : "=v"(d) : "v"(a), "v"(b), "v"(c)); return d;
}
__device__ __forceinline__ f32x2 pk_mul(f32x2 a, f32x2 b) {
    f32x2 d; asm("v_pk_mul_f32 %0, %1, %2" : "=v"(d) : "v"(a), "v"(b)); return d;
}
__device__ __forceinline__ f32x2 pk_add(f32x2 a, f32x2 b) {
    f32x2 d; asm("v_pk_add_f32 %0, %1, %2" : "=v"(d) : "v"(a), "v"(b)); return d;
}

__global__ __launch_bounds__(256) void grad_attn_kernel(
    const float* __restrict__ preds,
    const int*   __restrict__ mask_ids,
    const float* __restrict__ W1,
    const float* __restrict__ b1,
    const float* __restrict__ W2,
    float*       __restrict__ out)
{
    const int tid = threadIdx.x;
    const int bi  = blockIdx.x;

    if (bi >= NCOMPUTE) {
        // ---- pure copy region: cols [C_, V_) of 2 rows ----
        const int r0 = (bi - NCOMPUTE) * 2;
        #pragma unroll
        for (int r = 0; r < 2; ++r) {
            const float4* src = reinterpret_cast<const float4*>(preds + (size_t)(r0 + r) * V_ + C_);
            float4*       dst = reinterpret_cast<float4*>(out + (size_t)(r0 + r) * V_ + C_);
            #pragma unroll
            for (int j = tid; j < (V_ - C_) / 4; j += 256) dst[j] = src[j];
        }
        return;
    }

    const int chunk  = bi & 1;
    const int rowgrp = bi >> 1;
    const int b0 = rowgrp * NB;
    const int c  = chunk * CHUNK + tid;

    // ---- weights as NATURAL h-pairs (no broadcast needed); b2 cancels ----
    f32x2 w1a2[H_ / 2], w1b2[H_ / 2], bb2[H_ / 2], w2b2[H_ / 2];
    {
        const f32x2* W1p = reinterpret_cast<const f32x2*>(W1 + (size_t)c * 2 * H_);
        const f32x2* b1p = reinterpret_cast<const f32x2*>(b1 + (size_t)c * H_);
        const f32x2* W2p = reinterpret_cast<const f32x2*>(W2 + (size_t)c * H_);
        #pragma unroll
        for (int i = 0; i < H_ / 2; ++i) {
            w1a2[i] = W1p[i];
            w1b2[i] = W1p[H_ / 2 + i];
            bb2[i]  = b1p[i];
            w2b2[i] = W2p[i];
        }
    }

    int midx[M_];
    {
        const int4* mi = reinterpret_cast<const int4*>(mask_ids + (size_t)c * M_);
        int4 a = mi[0], b = mi[1];
        midx[0] = a.x; midx[1] = a.y; midx[2] = a.z; midx[3] = a.w;
        midx[4] = b.x; midx[5] = b.y; midx[6] = b.z; midx[7] = b.w;
    }

    // packed constants (materialized once, loop-invariant)
    const f32x2 c105 = {105.0f, 105.0f};
    const f32x2 c945 = {945.0f, 945.0f};
    const f32x2 c15  = {15.0f, 15.0f};
    const f32x2 c420 = {420.0f, 420.0f};
    const f32x2 two  = {2.0f, 2.0f};
    const f32x2 m1   = {-1.0f, -1.0f};

    #pragma unroll
    for (int r = 0; r < NB; ++r) {
        const float* row = preds + (size_t)(b0 + r) * V_;
        float ha = row[c];
        float hm[M_];
        #pragma unroll
        for (int m = 0; m < M_; ++m) hm[m] = row[midx[m]];

        f32x2 hav = {ha, ha};
        // pa[hh] = ha*w1a + b1, packed over h — computed once per row
        f32x2 pav[H_ / 2];
        #pragma unroll
        for (int i = 0; i < H_ / 2; ++i) pav[i] = pk_fma(hav, w1a2[i], bb2[i]);

        float score[M_];
        #pragma unroll
        for (int m = 0; m < M_; ++m) {
            f32x2 hmv = {hm[m], hm[m]};
            f32x2 acc = {0.0f, 0.0f};
            #pragma unroll
            for (int i = 0; i < H_ / 2; ++i) {
                f32x2 x  = pk_fma(hmv, w1b2[i], pav[i]);
                // Pade[5/4] tanh: x*(945+105y+y^2)/(945+420y+15y^2), y=x^2
                f32x2 y  = pk_mul(x, x);
                f32x2 n  = pk_add(y, c105);
                n        = pk_fma(y, n, c945);
                f32x2 dd = pk_fma(y, c15, c420);
                dd       = pk_fma(y, dd, c945);
                f32x2 xn = pk_mul(x, n);
                // zero-trans reciprocal: magic seed + 2 packed Newton
                f32x2 rc;
                rc.x = __uint_as_float(0x7EF311C3u - __float_as_uint(dd.x));
                rc.y = __uint_as_float(0x7EF311C3u - __float_as_uint(dd.y));
                f32x2 nd = pk_mul(dd, m1);
                rc = pk_mul(rc, pk_fma(nd, rc, two));
                rc = pk_mul(rc, pk_fma(nd, rc, two));
                f32x2 t  = pk_mul(xn, rc);
                t.x = __builtin_amdgcn_fmed3f(t.x, -1.0f, 1.0f);
                t.y = __builtin_amdgcn_fmed3f(t.y, -1.0f, 1.0f);
                acc = pk_fma(t, w2b2[i], acc);
            }
            score[m] = acc.x + acc.y;
        }

        // softmax over M (no max-subtract: |score| <= sum|w2| ~ 6, exp2 safe)
        float ex[M_], sum = 0.0f, ws = 0.0f;
        #pragma unroll
        for (int m = 0; m < M_; ++m) {
            ex[m] = fast_exp2(score[m] * LOG2E);
            sum += ex[m];
        }
        #pragma unroll
        for (int m = 0; m < M_; ++m) ws = fmaf(ex[m], hm[m], ws);
        float corrected = fmaxf(ha, fmaf(ws, fast_rcp(sum), 1e-6f));
        out[(size_t)(b0 + r) * V_ + c] = corrected;
    }
}

extern "C" void kernel_launch(void* const* d_in, const int* in_sizes, int n_in,
                              void* d_out, int out_size, void* d_ws, size_t ws_size,
                              hipStream_t stream) {
    const float* preds    = (const float*)d_in[0];
    const int*   mask_ids = (const int*)d_in[2];
    const float* W1       = (const float*)d_in[3];
    const float* b1       = (const float*)d_in[4];
    const float* W2       = (const float*)d_in[5];
    float* out = (float*)d_out;

    dim3 grid(NCOMPUTE + NCOPY);
    dim3 block(256);
    grad_attn_kernel<<<grid, block, 0, stream>>>(preds, mask_ids, W1, b1, W2, out);
}

// Round 7
// 43.023 us; speedup vs baseline: 1.1394x; 1.1394x over previous
//
#include <hip/hip_runtime.h>

#define B_ 2048
#define V_ 2048
#define C_ 512
#define M_ 8
#define H_ 16
#define NB 2            // rows per compute block
#define CHUNK 256       // columns per compute block == blockDim.x
#define NCOMPUTE ((C_ / CHUNK) * (B_ / NB))   // 2048 compute blocks
#define NCOPY (B_ / 2)                        // 1024 copy blocks, 2 rows each

typedef _Float16 h2 __attribute__((ext_vector_type(2)));
typedef __fp16 fp16x2_raw __attribute__((ext_vector_type(2)));

__device__ __forceinline__ float fast_exp2(float x) { return __builtin_amdgcn_exp2f(x); }
__device__ __forceinline__ float fast_rcp(float x)  { return __builtin_amdgcn_rcpf(x); }
// v_cvt_pkrtz_f16_f32 returns __fp16x2; bit-cast to our _Float16x2.
__device__ __forceinline__ h2 cvt_pk(float a, float b) {
    return __builtin_bit_cast(h2, __builtin_amdgcn_cvt_pkrtz(a, b));
}

#define LOG2E 1.4426950408889634f
#define XCLAMP 3.65f     // Pade[5/4] crosses 1.0 at x~3.651; tanh(3.65)=0.99866

__global__ __launch_bounds__(256) void grad_attn_kernel(
    const float* __restrict__ preds,
    const int*   __restrict__ mask_ids,
    const float* __restrict__ W1,
    const float* __restrict__ b1,
    const float* __restrict__ W2,
    float*       __restrict__ out)
{
    const int tid = threadIdx.x;
    const int bi  = blockIdx.x;

    if (bi >= NCOMPUTE) {
        // ---- pure copy region: cols [C_, V_) of 2 rows ----
        const int r0 = (bi - NCOMPUTE) * 2;
        #pragma unroll
        for (int r = 0; r < 2; ++r) {
            const float4* src = reinterpret_cast<const float4*>(preds + (size_t)(r0 + r) * V_ + C_);
            float4*       dst = reinterpret_cast<float4*>(out + (size_t)(r0 + r) * V_ + C_);
            #pragma unroll
            for (int j = tid; j < (V_ - C_) / 4; j += 256) dst[j] = src[j];
        }
        return;
    }

    const int chunk  = bi & 1;
    const int rowgrp = bi >> 1;
    const int b0 = rowgrp * NB;
    const int c  = chunk * CHUNK + tid;

    // ---- weights: w1a/b1 kept f32 (pa precision); w1b/w2 as packed f16 pairs ----
    float w1a[H_], bbf[H_];
    h2 w1b2[H_ / 2], w22[H_ / 2];
    {
        const float4* W1v = reinterpret_cast<const float4*>(W1 + (size_t)c * 2 * H_);
        const float4* b1v = reinterpret_cast<const float4*>(b1 + (size_t)c * H_);
        const float4* W2v = reinterpret_cast<const float4*>(W2 + (size_t)c * H_);
        #pragma unroll
        for (int i = 0; i < H_ / 4; ++i) {
            float4 a = W1v[i], bk = W1v[H_ / 4 + i], bv = b1v[i], wv = W2v[i];
            w1a[4*i+0] = a.x; w1a[4*i+1] = a.y; w1a[4*i+2] = a.z; w1a[4*i+3] = a.w;
            bbf[4*i+0] = bv.x; bbf[4*i+1] = bv.y; bbf[4*i+2] = bv.z; bbf[4*i+3] = bv.w;
            w1b2[2*i]     = cvt_pk(bk.x, bk.y);
            w1b2[2*i + 1] = cvt_pk(bk.z, bk.w);
            w22[2*i]      = cvt_pk(wv.x, wv.y);
            w22[2*i + 1]  = cvt_pk(wv.z, wv.w);
        }
    }

    int midx[M_];
    {
        const int4* mi = reinterpret_cast<const int4*>(mask_ids + (size_t)c * M_);
        int4 a = mi[0], b = mi[1];
        midx[0] = a.x; midx[1] = a.y; midx[2] = a.z; midx[3] = a.w;
        midx[4] = b.x; midx[5] = b.y; midx[6] = b.z; midx[7] = b.w;
    }

    const h2 clo  = {(_Float16)(-XCLAMP), (_Float16)(-XCLAMP)};
    const h2 chi  = {(_Float16)(XCLAMP),  (_Float16)(XCLAMP)};
    const h2 c105 = {(_Float16)105.0f, (_Float16)105.0f};
    const h2 c945 = {(_Float16)945.0f, (_Float16)945.0f};
    const h2 c15  = {(_Float16)15.0f,  (_Float16)15.0f};
    const h2 c420 = {(_Float16)420.0f, (_Float16)420.0f};
    const h2 ctwo = {(_Float16)2.0f,   (_Float16)2.0f};

    #pragma unroll
    for (int r = 0; r < NB; ++r) {
        const float* row = preds + (size_t)(b0 + r) * V_;
        float ha = row[c];
        float hm[M_];
        #pragma unroll
        for (int m = 0; m < M_; ++m) hm[m] = row[midx[m]];

        // pa[h] = ha*w1a[h] + b1[h] in f32, then packed to f16 pairs
        h2 pav[H_ / 2];
        #pragma unroll
        for (int i = 0; i < H_ / 2; ++i) {
            float p0 = fmaf(ha, w1a[2*i],     bbf[2*i]);
            float p1 = fmaf(ha, w1a[2*i + 1], bbf[2*i + 1]);
            pav[i] = cvt_pk(p0, p1);
        }

        float score[M_];
        #pragma unroll
        for (int m = 0; m < M_; ++m) {
            _Float16 hmh = (_Float16)hm[m];
            h2 hmv = {hmh, hmh};
            float acc = 0.0f;
            #pragma unroll
            for (int i = 0; i < H_ / 2; ++i) {
                h2 x = __builtin_elementwise_fma(hmv, w1b2[i], pav[i]);
                x = __builtin_elementwise_max(x, clo);
                x = __builtin_elementwise_min(x, chi);
                h2 y  = x * x;
                h2 s  = y + c105;
                h2 n  = __builtin_elementwise_fma(y, s, c945);     // num = y^2+105y+945
                h2 v  = __builtin_elementwise_fma(y, c15, c420);
                h2 d  = __builtin_elementwise_fma(y, v, c945);     // den = 15y^2+420y+945
                // packed f16 rcp: bit-magic seed (both halves via one u32 sub) + 2 Newton
                unsigned du = __builtin_bit_cast(unsigned, d);
                h2 rc = __builtin_bit_cast(h2, 0x77987798u - du);
                h2 nd = -d;
                rc = rc * __builtin_elementwise_fma(nd, rc, ctwo);
                rc = rc * __builtin_elementwise_fma(nd, rc, ctwo);
                h2 t = (x * n) * rc;                               // tanh approx, |t|<=1.0001
                acc = __builtin_amdgcn_fdot2(__builtin_bit_cast(fp16x2_raw, t),
                                             __builtin_bit_cast(fp16x2_raw, w22[i]),
                                             acc, false);          // v_dot2_f32_f16
            }
            score[m] = acc;
        }

        // softmax over M (no max-subtract: |score| <= sum|w2| ~ 6, exp2 safe)
        float ex[M_], sum = 0.0f, ws = 0.0f;
        #pragma unroll
        for (int m = 0; m < M_; ++m) {
            ex[m] = fast_exp2(score[m] * LOG2E);
            sum += ex[m];
        }
        #pragma unroll
        for (int m = 0; m < M_; ++m) ws = fmaf(ex[m], hm[m], ws);
        float corrected = fmaxf(ha, fmaf(ws, fast_rcp(sum), 1e-6f));
        out[(size_t)(b0 + r) * V_ + c] = corrected;
    }
}

extern "C" void kernel_launch(void* const* d_in, const int* in_sizes, int n_in,
                              void* d_out, int out_size, void* d_ws, size_t ws_size,
                              hipStream_t stream) {
    const float* preds    = (const float*)d_in[0];
    const int*   mask_ids = (const int*)d_in[2];
    const float* W1       = (const float*)d_in[3];
    const float* b1       = (const float*)d_in[4];
    const float* W2       = (const float*)d_in[5];
    float* out = (float*)d_out;

    dim3 grid(NCOMPUTE + NCOPY);
    dim3 block(256);
    grad_attn_kernel<<<grid, block, 0, stream>>>(preds, mask_ids, W1, b1, W2, out);
}

// Round 8
// 38.098 us; speedup vs baseline: 1.2867x; 1.1292x over previous
//
#include <hip/hip_runtime.h>

#define B_ 2048
#define V_ 2048
#define C_ 512
#define M_ 8
#define H_ 16
#define GATH (V_ - C_)        // 1536 gatherable cols per row
#define ROWS 2                // rows per block

__device__ __forceinline__ float fast_exp2(float x) { return __builtin_amdgcn_exp2f(x); }
__device__ __forceinline__ float fast_rcp(float x)  { return __builtin_amdgcn_rcpf(x); }

#define K_SCALE 2.885390081777927f      // 2*log2(e): tanh(x) = 1 - 2*rcp(exp2(K*x)+1)
#define LOG2E   1.4426950408889634f

// One block = 2 full rows: copy cols [512,2048) (staging them in LDS for the
// gathers) + compute cols [0,512). 1024 blocks, 256 threads.
__global__ __launch_bounds__(256, 4) void grad_attn_kernel(
    const float* __restrict__ preds,
    const int*   __restrict__ mask_ids,
    const float* __restrict__ W1,
    const float* __restrict__ b1,
    const float* __restrict__ W2,
    float*       __restrict__ out)
{
    __shared__ float smem[ROWS][GATH];   // 12 KB

    const int tid = threadIdx.x;
    const int r0  = blockIdx.x * ROWS;

    // ---- Phase A: copy + stage cols [C_, V_) of both rows ----
    #pragma unroll
    for (int k = 0; k < ROWS * (GATH / 4) / 256; ++k) {   // 3 iters
        int j  = tid + k * 256;
        int r  = j / (GATH / 4);
        int jj = j % (GATH / 4);
        const float4* src = reinterpret_cast<const float4*>(preds + (size_t)(r0 + r) * V_ + C_);
        float4 v = src[jj];
        reinterpret_cast<float4*>(out + (size_t)(r0 + r) * V_ + C_)[jj] = v;
        *reinterpret_cast<float4*>(&smem[r][4 * jj]) = v;
    }
    __syncthreads();

    // ---- Phase B: compute cols tid and tid+256 for both rows ----
    #pragma unroll
    for (int cc = 0; cc < C_ / 256; ++cc) {               // 2 cols per thread
        const int c = tid + cc * 256;

        // weights, K-prescaled; w2n = -2*w2 (base term cancels in softmax)
        float w1a[H_], w1b[H_], bb[H_], w2n[H_];
        {
            const float4* W1v = reinterpret_cast<const float4*>(W1 + (size_t)c * 2 * H_);
            const float4* b1v = reinterpret_cast<const float4*>(b1 + (size_t)c * H_);
            const float4* W2v = reinterpret_cast<const float4*>(W2 + (size_t)c * H_);
            #pragma unroll
            for (int i = 0; i < H_ / 4; ++i) {
                float4 a = W1v[i], bk = W1v[H_ / 4 + i], bv = b1v[i], wv = W2v[i];
                w1a[4*i+0] = a.x * K_SCALE;  w1a[4*i+1] = a.y * K_SCALE;
                w1a[4*i+2] = a.z * K_SCALE;  w1a[4*i+3] = a.w * K_SCALE;
                w1b[4*i+0] = bk.x * K_SCALE; w1b[4*i+1] = bk.y * K_SCALE;
                w1b[4*i+2] = bk.z * K_SCALE; w1b[4*i+3] = bk.w * K_SCALE;
                bb[4*i+0]  = bv.x * K_SCALE; bb[4*i+1]  = bv.y * K_SCALE;
                bb[4*i+2]  = bv.z * K_SCALE; bb[4*i+3]  = bv.w * K_SCALE;
                w2n[4*i+0] = -2.0f * wv.x;   w2n[4*i+1] = -2.0f * wv.y;
                w2n[4*i+2] = -2.0f * wv.z;   w2n[4*i+3] = -2.0f * wv.w;
            }
        }

        int midx[M_];
        {
            const int4* mi = reinterpret_cast<const int4*>(mask_ids + (size_t)c * M_);
            int4 a = mi[0], b = mi[1];
            midx[0] = a.x - C_; midx[1] = a.y - C_; midx[2] = a.z - C_; midx[3] = a.w - C_;
            midx[4] = b.x - C_; midx[5] = b.y - C_; midx[6] = b.z - C_; midx[7] = b.w - C_;
        }

        #pragma unroll
        for (int r = 0; r < ROWS; ++r) {
            const float ha = preds[(size_t)(r0 + r) * V_ + c];   // coalesced
            float hm[M_];
            #pragma unroll
            for (int m = 0; m < M_; ++m) hm[m] = smem[r][midx[m]];   // LDS gather

            float sc[M_];
            #pragma unroll
            for (int m = 0; m < M_; ++m) sc[m] = 0.0f;

            #pragma unroll
            for (int h = 0; h < H_; ++h) {
                const float pa  = fmaf(ha, w1a[h], bb[h]);
                const float wb  = w1b[h];
                const float w2h = w2n[h];
                #pragma unroll
                for (int m = 0; m < M_; ++m) {
                    float e = fast_exp2(fmaf(hm[m], wb, pa));
                    sc[m] = fmaf(fast_rcp(e + 1.0f), w2h, sc[m]);
                }
            }

            // softmax over M (uniform base dropped; |sc| small -> exp2 safe)
            float ex[M_], sum = 0.0f, ws = 0.0f;
            #pragma unroll
            for (int m = 0; m < M_; ++m) {
                ex[m] = fast_exp2(sc[m] * LOG2E);
                sum += ex[m];
            }
            #pragma unroll
            for (int m = 0; m < M_; ++m) ws = fmaf(ex[m], hm[m], ws);
            float corrected = fmaxf(ha, fmaf(ws, fast_rcp(sum), 1e-6f));
            out[(size_t)(r0 + r) * V_ + c] = corrected;
        }
    }
}

extern "C" void kernel_launch(void* const* d_in, const int* in_sizes, int n_in,
                              void* d_out, int out_size, void* d_ws, size_t ws_size,
                              hipStream_t stream) {
    const float* preds    = (const float*)d_in[0];
    const int*   mask_ids = (const int*)d_in[2];
    const float* W1       = (const float*)d_in[3];
    const float* b1       = (const float*)d_in[4];
    const float* W2       = (const float*)d_in[5];
    float* out = (float*)d_out;

    dim3 grid(B_ / ROWS);    // 1024 blocks
    dim3 block(256);
    grad_attn_kernel<<<grid, block, 0, stream>>>(preds, mask_ids, W1, b1, W2, out);
}